// Round 7
// baseline (106.700 us; speedup 1.0000x reference)
//
#include <hip/hip_runtime.h>

#define CC   14      // num labels
#define MAXT 13      // max trials
#define TPB  256     // one row per thread
#define RAMP_CAP 1.8f

// harmonic numbers, fp32 chain in reference cumsum order
constexpr float H2  = 1.0f + 0.5f;
constexpr float H3  = H2  + (1.0f/3.0f);
constexpr float H4  = H3  + 0.25f;
constexpr float H5  = H4  + 0.2f;
constexpr float H6  = H5  + (1.0f/6.0f);
constexpr float H7  = H6  + (1.0f/7.0f);
constexpr float H14 = H7 + 0.125f + (1.0f/9.0f) + 0.1f + (1.0f/11.0f)
                         + (1.0f/12.0f) + (1.0f/13.0f) + (1.0f/14.0f);

// align(4) vector types: gfx950 supports unaligned global vector loads
typedef float float4u __attribute__((ext_vector_type(4), aligned(4)));
typedef float float2u __attribute__((ext_vector_type(2), aligned(4)));
typedef int   int4u   __attribute__((ext_vector_type(4), aligned(4)));
typedef int   int2u   __attribute__((ext_vector_type(2), aligned(4)));

__global__ __launch_bounds__(TPB) void rwl_kernel(
    const float* __restrict__ inp, const int* __restrict__ target,
    const float* __restrict__ S, const float* __restrict__ rand_u,
    float* __restrict__ out, int B)
{
    __shared__ float s_red[4];
    const int tid = threadIdx.x;
    const int row = blockIdx.x * TPB + tid;

    float total = 0.f;
    if (row < B) {
        const float* xp = inp    + (size_t)row * CC;
        const int*   tp = target + (size_t)row * CC;
        const float* pu = rand_u + (size_t)row * (CC * MAXT);

        // ---- issue ALL loads up-front, unguarded: ~36 independent in flight ----
        float4u xv0 = __builtin_nontemporal_load((const float4u*)(xp));
        float4u xv1 = __builtin_nontemporal_load((const float4u*)(xp + 4));
        float4u xv2 = __builtin_nontemporal_load((const float4u*)(xp + 8));
        float2u xv3 = __builtin_nontemporal_load((const float2u*)(xp + 12));
        int4u   tv0 = __builtin_nontemporal_load((const int4u*)(tp));
        int4u   tv1 = __builtin_nontemporal_load((const int4u*)(tp + 4));
        int4u   tv2 = __builtin_nontemporal_load((const int4u*)(tp + 8));
        int2u   tv3 = __builtin_nontemporal_load((const int2u*)(tp + 12));

        float4u q0[CC], q1[CC];                 // trials 0..7 per label
        #pragma unroll
        for (int j = 0; j < CC; ++j) {
            q0[j] = __builtin_nontemporal_load((const float4u*)(pu + 13 * j));
            q1[j] = __builtin_nontemporal_load((const float4u*)(pu + 13 * j + 4));
        }

        float x[CC] = {xv0.x,xv0.y,xv0.z,xv0.w, xv1.x,xv1.y,xv1.z,xv1.w,
                       xv2.x,xv2.y,xv2.z,xv2.w, xv3.x,xv3.y};
        const int tg[CC] = {tv0.x,tv0.y,tv0.z,tv0.w, tv1.x,tv1.y,tv1.z,tv1.w,
                            tv2.x,tv2.y,tv2.z,tv2.w, tv3.x,tv3.y};

        unsigned pm = 0; float kap = 0.f;
        #pragma unroll
        for (int k = 0; k < CC; ++k) {
            if (tg[k] != 0) {
                pm |= (1u << k);
                kap += fminf(fmaxf(1.0f - x[k], 0.f), RAMP_CAP);
            } else {
                kap += 1.0f;                 // clip(1 - 0*x, 0, 1.8) = 1
            }
        }
        const int   nn   = CC - __popc(pm);
        const bool  vrow = (nn > 0);
        const float fnn  = (float)nn;

        // ---- branchless per-label compute ----
        float lw = 0.f;
        #pragma unroll
        for (int j = 0; j < CC; ++j) {
            const float e[8] = {q0[j].x,q0[j].y,q0[j].z,q0[j].w,
                                q1[j].x,q1[j].y,q1[j].z,q1[j].w};
            const float m1 = 1.0f - x[j];
            float nsum = 0.f; unsigned gm = 0; int cnt = 0;
            #pragma unroll
            for (int k = 0; k < CC; ++k) {
                if (!((pm >> k) & 1u)) {     // negatives in ascending k order
                    nsum += fminf(fmaxf(x[j] - x[k], 0.f), RAMP_CAP);
                    if (m1 + x[k] >= 0.f) gm |= (1u << cnt);  // ref association
                    ++cnt;
                }
            }
            unsigned bits = 0;
            #pragma unroll
            for (int t = 0; t < 8; ++t) {
                int ti = (int)(e[t] * fnn);  // trunc == astype(int32)
                ti = ti < 0 ? 0 : ti;
                ti = ti > nn - 1 ? nn - 1 : ti;
                bits |= ((gm >> ti) & 1u) << t;
            }
            const bool pos = (pm >> j) & 1u;
            // tail trials 8..12: only when unresolved AND resolvable (gm!=0).
            // gm==0 is the deterministic never-resolves case -> nt stays MAXT.
            if (pos && vrow && bits == 0u && gm != 0u) {
                #pragma unroll
                for (int t = 8; t < MAXT; ++t) {
                    int ti = (int)(pu[13 * j + t] * fnn);
                    ti = ti < 0 ? 0 : ti;
                    ti = ti > nn - 1 ? nn - 1 : ti;
                    bits |= ((gm >> ti) & 1u) << t;
                }
            }
            const int nt = bits ? __ffs(bits) : MAXT;     // num_trials
            const float wt = (nt == 1) ? H14 : (nt == 2) ? H7
                           : (nt == 3) ? H5  : (nt == 4) ? H4
                           : (nt <= 6) ? H3  : H2;        // L[13 // nt]
            lw += (pos && vrow) ? wt * nsum : 0.f;
        }

        const float si = (row <= 14) ? 1.0f : S[row - 14];  // coalesced S load
        total = si * (lw + 2.0f * kap);
    }

    // block reduction: wave shuffle, LDS across 4 waves, 1 atomic per block
    #pragma unroll
    for (int off = 32; off > 0; off >>= 1)
        total += __shfl_down(total, off, 64);
    if ((tid & 63) == 0) s_red[tid >> 6] = total;
    __syncthreads();
    if (tid == 0)
        atomicAdd(out, s_red[0] + s_red[1] + s_red[2] + s_red[3]);
}

extern "C" void kernel_launch(void* const* d_in, const int* in_sizes, int n_in,
                              void* d_out, int out_size, void* d_ws, size_t ws_size,
                              hipStream_t stream) {
    const float* inp    = (const float*)d_in[0];
    const int*   target = (const int*)d_in[1];
    const float* S      = (const float*)d_in[2];
    const float* ru     = (const float*)d_in[3];
    float*       out    = (float*)d_out;
    const int B = in_sizes[2];   // S has B elements

    // d_out is poisoned and not re-zeroed between replays: zero it each call
    hipMemsetAsync(out, 0, sizeof(float), stream);

    const int blocks = (B + TPB - 1) / TPB;
    rwl_kernel<<<blocks, TPB, 0, stream>>>(inp, target, S, ru, out, B);
}

// Round 8
// 47.801 us; speedup vs baseline: 2.2321x; 2.2321x over previous
//
#include <hip/hip_runtime.h>

#define CC   14      // num labels
#define MAXT 13      // max trials
#define TPB  256     // one row per thread
#define RAMP_CAP 1.8f

// harmonic numbers, fp32 chain in reference cumsum order
constexpr float H2  = 1.0f + 0.5f;
constexpr float H3  = H2  + (1.0f/3.0f);
constexpr float H4  = H3  + 0.25f;
constexpr float H5  = H4  + 0.2f;
constexpr float H6  = H5  + (1.0f/6.0f);
constexpr float H7  = H6  + (1.0f/7.0f);
constexpr float H14 = H7 + 0.125f + (1.0f/9.0f) + 0.1f + (1.0f/11.0f)
                         + (1.0f/12.0f) + (1.0f/13.0f) + (1.0f/14.0f);

// One positive label. J, PAR compile-time -> float4 phase SH static.
// Loads trials 0..3 (1 or 2 aligned float4); tail 4..12 is a ~0.3% path.
template<int PAR, int J>
__device__ __forceinline__ void do_label(unsigned pm, int nn, float fnn,
                                         const float* __restrict__ rowF,
                                         const float (&x)[CC], float& lw)
{
    if ((pm >> J) & 1u) {
        constexpr int SH = (J + 2 * PAR) & 3;        // (182*row+13J) mod 4
        const float* qp = rowF + (13 * J - SH);       // 16B-aligned
        float e[8];
        {
            float4 q0 = *(const float4*)(qp);
            e[0]=q0.x; e[1]=q0.y; e[2]=q0.z; e[3]=q0.w;
        }
        if constexpr (SH != 0) {                      // trials 0..3 spill into q1
            float4 q1 = *(const float4*)(qp + 4);
            e[4]=q1.x; e[5]=q1.y; e[6]=q1.z; e[7]=q1.w;
        }

        // one pass over row: neg_sum + resolving-negative bitmask (k-order)
        const float m1 = 1.0f - x[J];
        float nsum = 0.f; unsigned gm = 0; int cnt = 0;
        #pragma unroll
        for (int k = 0; k < CC; ++k) {
            if (!((pm >> k) & 1u)) {
                nsum += fminf(fmaxf(x[J] - x[k], 0.f), RAMP_CAP);
                if (m1 + x[k] >= 0.f) gm |= (1u << cnt);   // ref association
                ++cnt;
            }
        }

        unsigned bits = 0;
        #pragma unroll
        for (int t = 0; t < 4; ++t) {                 // trials 0..3, static idx
            int ti = (int)(e[SH + t] * fnn);          // trunc == astype(int32)
            ti = ti < 0 ? 0 : ti;
            ti = ti > nn - 1 ? nn - 1 : ti;
            bits |= ((gm >> ti) & 1u) << t;
        }
        // tail: only when unresolved AND resolvable (gm==0 -> nt stays MAXT)
        if (bits == 0u && gm != 0u) {                 // P ~ 0.24^4 ~ 0.3%
            #pragma unroll
            for (int t = 4; t < MAXT; ++t) {
                int ti = (int)(rowF[13 * J + t] * fnn);
                ti = ti < 0 ? 0 : ti;
                ti = ti > nn - 1 ? nn - 1 : ti;
                bits |= ((gm >> ti) & 1u) << t;
            }
        }
        const int nt = bits ? __ffs(bits) : MAXT;     // num_trials
        const float wt = (nt == 1) ? H14 : (nt == 2) ? H7
                       : (nt == 3) ? H5  : (nt == 4) ? H4
                       : (nt <= 6) ? H3  : H2;        // L[13 // nt]
        lw += wt * nsum;
    }
}

template<int PAR>
__device__ __forceinline__ float row_contrib(int row,
    const float* __restrict__ inp, const int* __restrict__ target,
    const float* __restrict__ S, const float* __restrict__ rand_u)
{
    float x[CC];
    {
        const float* b = inp + (size_t)row * CC;     // phase = 2*PAR
        if constexpr (PAR == 0) {
            float4 a0 = *(const float4*)(b);
            float4 a1 = *(const float4*)(b + 4);
            float4 a2 = *(const float4*)(b + 8);
            float2 a3 = *(const float2*)(b + 12);
            x[0]=a0.x; x[1]=a0.y; x[2]=a0.z; x[3]=a0.w;
            x[4]=a1.x; x[5]=a1.y; x[6]=a1.z; x[7]=a1.w;
            x[8]=a2.x; x[9]=a2.y; x[10]=a2.z; x[11]=a2.w;
            x[12]=a3.x; x[13]=a3.y;
        } else {
            float2 a0 = *(const float2*)(b);
            float4 a1 = *(const float4*)(b + 2);
            float4 a2 = *(const float4*)(b + 6);
            float4 a3 = *(const float4*)(b + 10);
            x[0]=a0.x; x[1]=a0.y;
            x[2]=a1.x; x[3]=a1.y; x[4]=a1.z; x[5]=a1.w;
            x[6]=a2.x; x[7]=a2.y; x[8]=a2.z; x[9]=a2.w;
            x[10]=a3.x; x[11]=a3.y; x[12]=a3.z; x[13]=a3.w;
        }
    }
    unsigned pm = 0; float kap = 0.f;
    {
        const int* b = target + (size_t)row * CC;
        int tg[CC];
        if constexpr (PAR == 0) {
            int4 a0 = *(const int4*)(b);
            int4 a1 = *(const int4*)(b + 4);
            int4 a2 = *(const int4*)(b + 8);
            int2 a3 = *(const int2*)(b + 12);
            tg[0]=a0.x; tg[1]=a0.y; tg[2]=a0.z; tg[3]=a0.w;
            tg[4]=a1.x; tg[5]=a1.y; tg[6]=a1.z; tg[7]=a1.w;
            tg[8]=a2.x; tg[9]=a2.y; tg[10]=a2.z; tg[11]=a2.w;
            tg[12]=a3.x; tg[13]=a3.y;
        } else {
            int2 a0 = *(const int2*)(b);
            int4 a1 = *(const int4*)(b + 2);
            int4 a2 = *(const int4*)(b + 6);
            int4 a3 = *(const int4*)(b + 10);
            tg[0]=a0.x; tg[1]=a0.y;
            tg[2]=a1.x; tg[3]=a1.y; tg[4]=a1.z; tg[5]=a1.w;
            tg[6]=a2.x; tg[7]=a2.y; tg[8]=a2.z; tg[9]=a2.w;
            tg[10]=a3.x; tg[11]=a3.y; tg[12]=a3.z; tg[13]=a3.w;
        }
        #pragma unroll
        for (int k = 0; k < CC; ++k) {
            if (tg[k] != 0) {
                pm |= (1u << k);
                kap += fminf(fmaxf(1.0f - x[k], 0.f), RAMP_CAP);
            } else {
                kap += 1.0f;             // clip(1 - 0*x, 0, 1.8) = 1
            }
        }
    }
    const int nn = CC - __popc(pm);

    float lw = 0.f;
    if (pm != 0u && nn > 0) {
        const float fnn = (float)nn;
        const float* rowF = rand_u + (size_t)row * (CC * MAXT);
        do_label<PAR, 0>(pm, nn, fnn, rowF, x, lw);
        do_label<PAR, 1>(pm, nn, fnn, rowF, x, lw);
        do_label<PAR, 2>(pm, nn, fnn, rowF, x, lw);
        do_label<PAR, 3>(pm, nn, fnn, rowF, x, lw);
        do_label<PAR, 4>(pm, nn, fnn, rowF, x, lw);
        do_label<PAR, 5>(pm, nn, fnn, rowF, x, lw);
        do_label<PAR, 6>(pm, nn, fnn, rowF, x, lw);
        do_label<PAR, 7>(pm, nn, fnn, rowF, x, lw);
        do_label<PAR, 8>(pm, nn, fnn, rowF, x, lw);
        do_label<PAR, 9>(pm, nn, fnn, rowF, x, lw);
        do_label<PAR,10>(pm, nn, fnn, rowF, x, lw);
        do_label<PAR,11>(pm, nn, fnn, rowF, x, lw);
        do_label<PAR,12>(pm, nn, fnn, rowF, x, lw);
        do_label<PAR,13>(pm, nn, fnn, rowF, x, lw);
    }
    const float si = (row <= 14) ? 1.0f : S[row - 14];
    return si * (lw + 2.0f * kap);
}

__global__ __launch_bounds__(TPB, 4) void rwl_kernel(
    const float* __restrict__ inp, const int* __restrict__ target,
    const float* __restrict__ S, const float* __restrict__ rand_u,
    float* __restrict__ out, int B)
{
    __shared__ float s_red[4];
    const int tid  = threadIdx.x;
    const int lane = tid & 63;
    const int wid  = tid >> 6;
    // interleaved mapping: wave-uniform row parity, 1 row/thread, full grid.
    // waves 0,1 cover base..base+127 (even/odd); waves 2,3 cover +128..+255.
    const int row = blockIdx.x * TPB + ((wid >> 1) << 7) + (lane << 1) + (wid & 1);
    const int par = __builtin_amdgcn_readfirstlane(wid & 1);   // scalar branch

    float total = 0.f;
    if (row < B) {
        if (par == 0) total = row_contrib<0>(row, inp, target, S, rand_u);
        else          total = row_contrib<1>(row, inp, target, S, rand_u);
    }

    // block reduction: wave shuffle, LDS across 4 waves, 1 atomic per block
    #pragma unroll
    for (int off = 32; off > 0; off >>= 1)
        total += __shfl_down(total, off, 64);
    if ((tid & 63) == 0) s_red[wid] = total;
    __syncthreads();
    if (tid == 0)
        atomicAdd(out, s_red[0] + s_red[1] + s_red[2] + s_red[3]);
}

extern "C" void kernel_launch(void* const* d_in, const int* in_sizes, int n_in,
                              void* d_out, int out_size, void* d_ws, size_t ws_size,
                              hipStream_t stream) {
    const float* inp    = (const float*)d_in[0];
    const int*   target = (const int*)d_in[1];
    const float* S      = (const float*)d_in[2];
    const float* ru     = (const float*)d_in[3];
    float*       out    = (float*)d_out;
    const int B = in_sizes[2];   // S has B elements

    // d_out is poisoned and not re-zeroed between replays: zero it each call
    hipMemsetAsync(out, 0, sizeof(float), stream);

    const int blocks = (B + TPB - 1) / TPB;
    rwl_kernel<<<blocks, TPB, 0, stream>>>(inp, target, S, ru, out, B);
}